// Round 6
// baseline (7222.952 us; speedup 1.0000x reference)
//
#include <hip/hip_runtime.h>
#include <math.h>

#define BB 128
#define TT 512
#define FF 128
#define HH 512
#define NR 2048      // gate rows, row = 4*j + g
#define HB (HH*BB)   // 65536 words per h state
#define FLS 16       // flag stride (ints): one flag per 64B line

typedef __attribute__((ext_vector_type(8))) short short8;   // 8 bf16
typedef __attribute__((ext_vector_type(4))) float f32x4;    // MFMA C/D frag
typedef unsigned int uint;
typedef unsigned short ushort;
typedef unsigned long long u64;

#define MFMA __builtin_amdgcn_mfma_f32_16x16x32_bf16
#define AT_LD(p)   __hip_atomic_load((p), __ATOMIC_RELAXED, __HIP_MEMORY_SCOPE_AGENT)
#define AT_ST(p,v) __hip_atomic_store((p), (v), __ATOMIC_RELAXED, __HIP_MEMORY_SCOPE_AGENT)
#define PLD(p)     (*(p))
// opaque-register pin: forbids rematerialization of the loaded value
#define PIN8(v)    asm volatile("" : "+v"(v))

__device__ __forceinline__ ushort f2bf(float f) {           // fp32 -> bf16 RNE
  uint u = __float_as_uint(f);
  u += 0x7fff + ((u >> 16) & 1);
  return (ushort)(u >> 16);
}
__device__ __forceinline__ float bfh(ushort h) { return __uint_as_float(((uint)h) << 16); }
__device__ __forceinline__ u64 pk2f(float a, float b) {
  return ((u64)__float_as_uint(b) << 32) | (u64)__float_as_uint(a);
}
__device__ __forceinline__ float ftanh(float v) {           // branch-free tanh
  float t = __expf(2.f * v);
  return 1.f - 2.f / (t + 1.f);
}
// 8 packed words (hi16|lo16) -> hi/lo short8 B-frags via v_perm (1 op/dword)
__device__ __forceinline__ void split8(const uint* w, short8& bh, short8& bl) {
  union { short8 v; uint d[4]; } H, Lo;
#pragma unroll
  for (int d = 0; d < 4; ++d) {
    H.d[d]  = __builtin_amdgcn_perm(w[2 * d + 1], w[2 * d], 0x07060302u);
    Lo.d[d] = __builtin_amdgcn_perm(w[2 * d + 1], w[2 * d], 0x05040100u);
  }
  bh = H.v; bl = Lo.v;
}

// ---------------- prep kernels ----------------

__global__ __launch_bounds__(256) void k_zero(float* __restrict__ p, int n) {
  int i = blockIdx.x * 256 + threadIdx.x;
  if (i < n) p[i] = 0.f;
}

// bias [2048] (col = g*512 + j) -> bp[j*4+g]
__global__ __launch_bounds__(256) void k_rearr_b(const float* __restrict__ src,
                                                 float* __restrict__ dst) {
  int idx = blockIdx.x * 256 + threadIdx.x;   // 2048
  int j = idx & 511, g = idx >> 9;
  dst[j * 4 + g] = src[idx];
}

// [K][2048] matrix -> A-fragment order, bf16 hi/lo split. KT=1<<ktsh k-tiles.
__global__ __launch_bounds__(256) void k_pack_A(const float* __restrict__ src,
                                                ushort* __restrict__ dst, int ktsh) {
  int idx = blockIdx.x * 256 + threadIdx.x;
  int KTm1 = (1 << ktsh) - 1;
  int j8 = idx & 7;
  int L = (idx >> 3) & 63;
  int kt = (idx >> 9) & KTm1;
  int jb = idx >> (9 + ktsh);
  int k = kt * 32 + (L >> 4) * 8 + j8;
  int m = L & 15;
  int j = jb * 4 + (m >> 2);
  int g = m & 3;
  float v = src[(size_t)k * NR + g * HH + j];
  ushort hi = f2bf(v);
  ushort lo = f2bf(v - bfh(hi));
  size_t base = ((size_t)((jb << ktsh) + kt) * 64 + L) * 16;
  dst[base + j8] = hi;
  dst[base + 8 + j8] = lo;
}

// ---------------- fused persistent 2-layer LSTM, specialized + K-split ------
// Structure/protocol = R5 (passed). Changes:
// (1) resident A-frags PINNED via opaque-register asm after load -> compiler
//     cannot rematerialize the U loads inside the serial G-loop;
// (2) phase-B h2 ring TRANSPOSED [slot][col][j]: consumer loads become 8
//     consecutive dwords per kt -> u64 atomic loads (2x fewer instructions on
//     the bypass path); producer stores are lane-scattered dwords (same byte
//     traffic / L3-line count); k_dense reads the transposed slot 3;
// (3) everything else byte-identical to R5.
__global__ __launch_bounds__(256, 1) void k_fused(
    const float* __restrict__ x,
    const ushort* __restrict__ W1pk, const ushort* __restrict__ U1pk,
    const float* __restrict__ bp1,
    const ushort* __restrict__ W2pk, const ushort* __restrict__ U2pk,
    const float* __restrict__ bp2,
    uint* __restrict__ seq, uint* __restrict__ ring,
    float4* __restrict__ xzr,                              // 8-slot gate ring
    int* __restrict__ hflags, int* __restrict__ pflags) {
  int tid = threadIdx.x;
  int L = tid & 63;
  int w = tid >> 6;
  int q = L >> 4, n = L & 15;
  int h = w & 1, p = w >> 1;      // K-half, row-tile pair
  bool isrec = (blockIdx.x < 128);
  int b = isrec ? blockIdx.x : (blockIdx.x - 128);
  int ch = b & 3, jb4 = b >> 2;
  int rt0 = jb4 * 4 + 2 * p;      // partial row-tiles rt0, rt0+1
  int jbp_own = rt0 + h;          // row-tile this wave finishes
  int j_own = jbp_own * 4 + q;    // this lane's hidden unit (epilogue)
  int col0 = ch * 32 + n;         // col-tile 0; tile 1 at +16
  int pidx = b * FLS;
  int rgive = 2 * p + 1 - h;      // LDS slot given away (block-local rt)
  int rkeep = 2 * p + h;

  __shared__ f32x4 xch[4][2][64]; // [local rt][ct][lane] partial exchange

  short8 uh[2][8], ul[2][8];      // resident A-frags: 2 rts x 8 kts (K-half)

// load + partial GEMM for one col-tile over this wave's K-half (phase A /
// projB: untransposed seq, plain loads). HS includes the +256h*BB offset.
#define LOADMM(HS, COLC, ZP) {                                           \
    uint wv[8][8];                                                       \
    const uint* hc = (HS) + (size_t)(q * 8) * BB + (COLC);               \
    _Pragma("unroll")                                                    \
    for (int kk = 0; kk < 8; ++kk)                                       \
      _Pragma("unroll")                                                  \
      for (int u = 0; u < 8; ++u)                                        \
        wv[kk][u] = PLD(hc + (size_t)(kk * 32 + u) * BB);                \
    f32x4 A0[2], A1[2], A2[2];                                           \
    _Pragma("unroll")                                                    \
    for (int r = 0; r < 2; ++r) {                                        \
      A0[r] = (f32x4){0.f, 0.f, 0.f, 0.f}; A1[r] = A0[r]; A2[r] = A0[r]; \
    }                                                                    \
    _Pragma("unroll")                                                    \
    for (int kk = 0; kk < 8; ++kk) {                                     \
      short8 bh, bl;                                                     \
      split8(wv[kk], bh, bl);                                            \
      _Pragma("unroll")                                                  \
      for (int r = 0; r < 2; ++r) {                                      \
        A0[r] = MFMA(uh[r][kk], bh, A0[r], 0, 0, 0);                     \
        A1[r] = MFMA(ul[r][kk], bh, A1[r], 0, 0, 0);                     \
        A2[r] = MFMA(uh[r][kk], bl, A2[r], 0, 0, 0);                     \
      }                                                                  \
    }                                                                    \
    ZP[0] = A0[0] + A1[0] + A2[0];                                       \
    ZP[1] = A0[1] + A1[1] + A2[1];                                       \
  }

// phase-B variant: transposed ring [slot][col][j], u64 agent-atomic loads.
// Lane reads k = 256h + kk*32 + q*8 + u (u=0..7) at col COLC -> 4 u64/kt.
#define LOADMM_T(SLOT, COLC, ZP) {                                       \
    u64 wq[8][4];                                                        \
    const u64* hc = (const u64*)(ring + (size_t)(SLOT) * HB              \
                    + (size_t)(COLC) * HH + 256 * h + q * 8);            \
    _Pragma("unroll")                                                    \
    for (int kk = 0; kk < 8; ++kk)                                       \
      _Pragma("unroll")                                                  \
      for (int u4 = 0; u4 < 4; ++u4)                                     \
        wq[kk][u4] = AT_LD(hc + kk * 16 + u4);                           \
    f32x4 A0[2], A1[2], A2[2];                                           \
    _Pragma("unroll")                                                    \
    for (int r = 0; r < 2; ++r) {                                        \
      A0[r] = (f32x4){0.f, 0.f, 0.f, 0.f}; A1[r] = A0[r]; A2[r] = A0[r]; \
    }                                                                    \
    _Pragma("unroll")                                                    \
    for (int kk = 0; kk < 8; ++kk) {                                     \
      uint wv8[8];                                                       \
      _Pragma("unroll")                                                  \
      for (int u4 = 0; u4 < 4; ++u4) {                                   \
        wv8[2 * u4]     = (uint)wq[kk][u4];                              \
        wv8[2 * u4 + 1] = (uint)(wq[kk][u4] >> 32);                      \
      }                                                                  \
      short8 bh, bl;                                                     \
      split8(wv8, bh, bl);                                               \
      _Pragma("unroll")                                                  \
      for (int r = 0; r < 2; ++r) {                                      \
        A0[r] = MFMA(uh[r][kk], bh, A0[r], 0, 0, 0);                     \
        A1[r] = MFMA(ul[r][kk], bh, A1[r], 0, 0, 0);                     \
        A2[r] = MFMA(uh[r][kk], bl, A2[r], 0, 0, 0);                     \
      }                                                                  \
    }                                                                    \
    ZP[0] = A0[0] + A1[0] + A2[0];                                       \
    ZP[1] = A0[1] + A1[1] + A2[1];                                       \
  }

// activation for one col-tile from a summed z (f32x4) + xz scalars
#define ACT(ZV, X0, X1, X2, X3, CREF, WORD) {                            \
    float z0_ = (ZV).x + (X0), z1_ = (ZV).y + (X1);                      \
    float z2_ = (ZV).z + (X2), z3_ = (ZV).w + (X3);                      \
    float ig = 1.f / (1.f + __expf(-z0_));                               \
    float fg = 1.f / (1.f + __expf(-z1_));                               \
    float gg = ftanh(z2_);                                               \
    float og = 1.f / (1.f + __expf(-z3_));                               \
    (CREF) = fg * (CREF) + ig * gg;                                      \
    float hn = og * ftanh(CREF);                                         \
    ushort hh = f2bf(hn);                                                \
    (WORD) = (((uint)hh) << 16) | (uint)f2bf(hn - bfh(hh));              \
  }

#define PIN_ALL() { _Pragma("unroll") for (int r = 0; r < 2; ++r)        \
    _Pragma("unroll") for (int kk = 0; kk < 8; ++kk) {                   \
      PIN8(uh[r][kk]); PIN8(ul[r][kk]); } }

  if (isrec) {
#pragma unroll
    for (int r = 0; r < 2; ++r)
#pragma unroll
      for (int kk = 0; kk < 8; ++kk) {
        const ushort* pp = U1pk + (((size_t)(rt0 + r) * 16 + (8 * h + kk)) * 64 + L) * 16;
        uh[r][kk] = *(const short8*)(pp); ul[r][kk] = *(const short8*)(pp + 8);
      }
    PIN_ALL();
    float c0 = 0.f, c1 = 0.f;     // carried; c2_0 = c1_T at phase switch
    int fidx = ((16 * h + (L & 15)) * 4 + ch) * FLS;   // this K-half's flags

#pragma unroll 1
    for (int G = 0; G < 2 * TT; ++G) {
      if (G == TT) {
#pragma unroll
        for (int r = 0; r < 2; ++r)
#pragma unroll
          for (int kk = 0; kk < 8; ++kk) {
            const ushort* pp = U2pk + (((size_t)(rt0 + r) * 16 + (8 * h + kk)) * 64 + L) * 16;
            uh[r][kk] = *(const short8*)(pp); ul[r][kk] = *(const short8*)(pp + 8);
          }
        PIN_ALL();
      }
      // per-wave poll: this K-half's producers at >= G, partner xz at >= G+1
      while (true) {
        int hf = AT_LD(hflags + fidx);
        int pf = AT_LD(pflags + pidx);
        if (__all((hf >= G) && (pf >= G + 1))) break;
      }
      asm volatile("" ::: "memory");
      // xz for the owner unit (8-slot ring, bypass; long latency -> issue 1st)
      const u64* xpa = (const u64*)(xzr + ((size_t)(G & 7) * HB + (size_t)j_own * BB + col0));
      const u64* xpb = (const u64*)(xzr + ((size_t)(G & 7) * HB + (size_t)j_own * BB + col0 + 16));
      u64 qa0 = AT_LD(xpa), qa1 = AT_LD(xpa + 1);
      u64 qb0 = AT_LD(xpb), qb1 = AT_LD(xpb + 1);

      f32x4 zp0[2], zp1[2];       // partials per rt, ct0/ct1
      if (G != 0) {
        if (G < TT) {             // phase A: seq, write-once -> plain loads
          const uint* hs = seq + (size_t)(G - 1) * HB + (size_t)(256 * h) * BB;
          LOADMM(hs, col0, zp0);
          LOADMM(hs, col0 + 16, zp1);
        } else {                  // phase B: transposed ring -> u64 atomics
          int slot = (G - 1) & 3;
          LOADMM_T(slot, col0, zp0);
          LOADMM_T(slot, col0 + 16, zp1);
        }
      } else {
        zp0[0] = (f32x4){0.f, 0.f, 0.f, 0.f}; zp0[1] = zp0[0];
        zp1[0] = zp0[0]; zp1[1] = zp0[0];
      }
      // exchange: give the other rt's partials, keep own
      xch[rgive][0][L] = h ? zp0[0] : zp0[1];
      xch[rgive][1][L] = h ? zp1[0] : zp1[1];
      __syncthreads();
      f32x4 z0 = (h ? zp0[1] : zp0[0]) + xch[rkeep][0][L];
      f32x4 z1 = (h ? zp1[1] : zp1[0]) + xch[rkeep][1][L];

      uint wd0, wd1;
      ACT(z0, __uint_as_float((uint)qa0), __uint_as_float((uint)(qa0 >> 32)),
          __uint_as_float((uint)qa1), __uint_as_float((uint)(qa1 >> 32)), c0, wd0);
      ACT(z1, __uint_as_float((uint)qb0), __uint_as_float((uint)(qb0 >> 32)),
          __uint_as_float((uint)qb1), __uint_as_float((uint)(qb1 >> 32)), c1, wd1);

      if (G < TT) {
        AT_ST(&seq[(size_t)G * HB + (size_t)j_own * BB + col0], wd0);
        AT_ST(&seq[(size_t)G * HB + (size_t)j_own * BB + col0 + 16], wd1);
        if (G == TT - 1) {        // seed h2(-1) into transposed ring slot 3
          AT_ST(&ring[(size_t)3 * HB + (size_t)col0 * HH + j_own], wd0);
          AT_ST(&ring[(size_t)3 * HB + (size_t)(col0 + 16) * HH + j_own], wd1);
        }
      } else {
        AT_ST(&ring[(size_t)(G & 3) * HB + (size_t)col0 * HH + j_own], wd0);
        AT_ST(&ring[(size_t)(G & 3) * HB + (size_t)(col0 + 16) * HH + j_own], wd1);
      }
      __syncthreads();            // drain stores of all 4 waves + LDS reuse
      if (tid == 0) AT_ST(hflags + pidx, G + 1);
    }
  } else {
    // ---------------- PROJ block (K-split identical) ----------------
#pragma unroll
    for (int r = 0; r < 2; ++r)
#pragma unroll
      for (int kk = 0; kk < 2; ++kk) {
        const ushort* pp = W1pk + (((size_t)(rt0 + r) * 4 + (2 * h + kk)) * 64 + L) * 16;
        uh[r][kk] = *(const short8*)(pp); ul[r][kk] = *(const short8*)(pp + 8);
      }
    float4 bv = *(const float4*)(bp1 + j_own * 4);

#pragma unroll 1
    for (int G = 0; G < 2 * TT; ++G) {
      if (G == TT) {              // layer 2: W2 frags resident + bias
#pragma unroll
        for (int r = 0; r < 2; ++r)
#pragma unroll
          for (int kk = 0; kk < 8; ++kk) {
            const ushort* pp = W2pk + (((size_t)(rt0 + r) * 16 + (8 * h + kk)) * 64 + L) * 16;
            uh[r][kk] = *(const short8*)(pp); ul[r][kk] = *(const short8*)(pp + 8);
          }
        PIN_ALL();
        bv = *(const float4*)(bp2 + j_own * 4);
      }
      // throttle: slot G&7 last consumed by partner at G-8 -> hflag >= G-7
      if (G >= 8) {
        while (AT_LD(hflags + pidx) < G - 7) __builtin_amdgcn_s_sleep(1);
      }
      asm volatile("" ::: "memory");

      f32x4 zp0[2], zp1[2];
      if (G < TT) {
        // xz1 = W1 * x(G): this wave's 2 k-tiles (kt = 2h+kk)
#pragma unroll
        for (int r = 0; r < 2; ++r) {
          zp0[r] = (f32x4){0.f, 0.f, 0.f, 0.f}; zp1[r] = zp0[r];
        }
#define PROJA_CT(COLC, ZP) {                                             \
        f32x4 P0[2], P1[2], P2[2];                                       \
        _Pragma("unroll")                                                \
        for (int r = 0; r < 2; ++r) {                                    \
          P0[r] = (f32x4){0.f, 0.f, 0.f, 0.f}; P1[r] = P0[r]; P2[r] = P0[r]; \
        }                                                                \
        const float* xp = x + ((size_t)(COLC) * TT + G) * FF + q * 8 + 64 * h; \
        _Pragma("unroll")                                                \
        for (int kk = 0; kk < 2; ++kk) {                                 \
          float4 v0 = *(const float4*)(xp + kk * 32);                    \
          float4 v1 = *(const float4*)(xp + kk * 32 + 4);                \
          float xf[8] = {v0.x, v0.y, v0.z, v0.w, v1.x, v1.y, v1.z, v1.w}; \
          short8 xh, xl;                                                 \
          _Pragma("unroll")                                              \
          for (int u = 0; u < 8; ++u) {                                  \
            ushort hi = f2bf(xf[u]);                                     \
            xl[u] = (short)f2bf(xf[u] - bfh(hi));                        \
            xh[u] = (short)hi;                                           \
          }                                                              \
          _Pragma("unroll")                                              \
          for (int r = 0; r < 2; ++r) {                                  \
            P0[r] = MFMA(uh[r][kk], xh, P0[r], 0, 0, 0);                 \
            P1[r] = MFMA(ul[r][kk], xh, P1[r], 0, 0, 0);                 \
            P2[r] = MFMA(uh[r][kk], xl, P2[r], 0, 0, 0);                 \
          }                                                              \
        }                                                                \
        ZP[0] = P0[0] + P1[0] + P2[0];                                   \
        ZP[1] = P0[1] + P1[1] + P2[1];                                   \
      }
        PROJA_CT(col0, zp0);
        PROJA_CT(col0 + 16, zp1);
      } else {
        // xz2 = W2 * h1(sp): seq final -> plain loads
        int sp = G - TT;
        const uint* hs = seq + (size_t)sp * HB + (size_t)(256 * h) * BB;
        LOADMM(hs, col0, zp0);
        LOADMM(hs, col0 + 16, zp1);
      }
      // exchange + owner writes xz (+bias) to the 8-slot ring
      xch[rgive][0][L] = h ? zp0[0] : zp0[1];
      xch[rgive][1][L] = h ? zp1[0] : zp1[1];
      __syncthreads();
      f32x4 z0 = (h ? zp0[1] : zp0[0]) + xch[rkeep][0][L];
      f32x4 z1 = (h ? zp1[1] : zp1[0]) + xch[rkeep][1][L];
      {
        u64* dp = (u64*)(xzr + ((size_t)(G & 7) * HB + (size_t)j_own * BB + col0));
        AT_ST(dp, pk2f(z0.x + bv.x, z0.y + bv.y));
        AT_ST(dp + 1, pk2f(z0.z + bv.z, z0.w + bv.w));
        u64* dq = (u64*)(xzr + ((size_t)(G & 7) * HB + (size_t)j_own * BB + col0 + 16));
        AT_ST(dq, pk2f(z1.x + bv.x, z1.y + bv.y));
        AT_ST(dq + 1, pk2f(z1.z + bv.z, z1.w + bv.w));
      }
      __syncthreads();
      if (tid == 0) AT_ST(pflags + pidx, G + 1);
    }
  }
}

// ---------------- dense + softmax (transposed ring slot 3: [col][j]) --------
__global__ __launch_bounds__(64) void k_dense(const uint* __restrict__ h2,
                                              const float* __restrict__ Wd,
                                              const float* __restrict__ bd,
                                              float* __restrict__ out) {
  int b = blockIdx.x * 64 + threadIdx.x;
  float acc[10];
#pragma unroll
  for (int c = 0; c < 10; ++c) acc[c] = bd[c];
  for (int k = 0; k < HH; ++k) {
    uint w = h2[(size_t)b * HH + k];
    float hv = __uint_as_float(w & 0xffff0000u) + __uint_as_float(w << 16);
#pragma unroll
    for (int c = 0; c < 10; ++c) acc[c] = fmaf(hv, Wd[k * 10 + c], acc[c]);
  }
  float m = acc[0];
#pragma unroll
  for (int c = 1; c < 10; ++c) m = fmaxf(m, acc[c]);
  float s = 0.f;
#pragma unroll
  for (int c = 0; c < 10; ++c) { acc[c] = __expf(acc[c] - m); s += acc[c]; }
  float inv = 1.f / s;
#pragma unroll
  for (int c = 0; c < 10; ++c) out[b * 10 + c] = acc[c] * inv;
}

// ---------------- host ----------------
extern "C" void kernel_launch(void* const* d_in, const int* in_sizes, int n_in,
                              void* d_out, int out_size, void* d_ws, size_t ws_size,
                              hipStream_t stream) {
  const float* x  = (const float*)d_in[0];
  const float* W1 = (const float*)d_in[1];
  const float* U1 = (const float*)d_in[2];
  const float* b1 = (const float*)d_in[3];
  const float* W2 = (const float*)d_in[4];
  const float* U2 = (const float*)d_in[5];
  const float* b2 = (const float*)d_in[6];
  const float* Wd = (const float*)d_in[7];
  const float* bd = (const float*)d_in[8];
  float* out = (float*)d_out;

  // workspace layout (~157 MB, < proven 181 MB)
  uint*   seq   = (uint*)d_ws;                      // [512][HB]   128 MB
  uint*   ring  = seq + (size_t)TT * HB;            // [4][HB] transposed 1 MB
  float4* xzr   = (float4*)(ring + (size_t)4 * HB); // [8][HB] f4    8 MB
  ushort* W1pk  = (ushort*)(xzr + (size_t)8 * HB);  //   524,288 ush
  ushort* U1pk  = W1pk + (size_t)524288;            // 2,097,152 ush
  ushort* U2pk  = U1pk + (size_t)2097152;           // 2,097,152 ush
  ushort* W2pk  = U2pk + (size_t)2097152;           // 2,097,152 ush
  float*  bp1   = (float*)(W2pk + (size_t)2097152); // 2,048 f
  float*  bp2   = bp1 + NR;                         // 2,048 f
  int*    hflags = (int*)(bp2 + NR);                // 128*FLS ints
  int*    pflags = hflags + 128 * FLS;              // 128*FLS ints

  k_zero<<<16, 256, 0, stream>>>((float*)hflags, 2 * 128 * FLS);
  k_rearr_b<<<8, 256, 0, stream>>>(b1, bp1);
  k_rearr_b<<<8, 256, 0, stream>>>(b2, bp2);
  k_pack_A<<<1024, 256, 0, stream>>>(W1, W1pk, 2);   // K=128 -> 4 k-tiles
  k_pack_A<<<4096, 256, 0, stream>>>(U1, U1pk, 4);   // K=512 -> 16 k-tiles
  k_pack_A<<<4096, 256, 0, stream>>>(U2, U2pk, 4);
  k_pack_A<<<4096, 256, 0, stream>>>(W2, W2pk, 4);

  k_fused<<<256, 256, 0, stream>>>(x, W1pk, U1pk, bp1, W2pk, U2pk, bp2,
                                   seq, ring, xzr, hflags, pflags);
  k_dense<<<2, 64, 0, stream>>>(ring + (size_t)3 * HB, Wd, bd, out);
}